// Round 1
// baseline (3984.034 us; speedup 1.0000x reference)
//
#include <hip/hip_runtime.h>

#define LL 8
#define DD 1024
#define VV 32000
#define SS 2048
#define BB 2
#define NROWS 4096          // B*S
#define DT_STEP 0.055f      // 0.5*(dt_min+dt_max)
#define HALF_DT 0.0275f
#define TUNNEL_SCALE 1.55f  // 1 + dt/dt_max

typedef __attribute__((ext_vector_type(8))) short bf16x8;
typedef __attribute__((ext_vector_type(4))) float f32x4;

static __device__ __forceinline__ float bf2f(unsigned short u){
  union { unsigned int i; float f; } v; v.i = ((unsigned int)u) << 16; return v.f;
}
static __device__ __forceinline__ unsigned short f2bf(float f){
  union { float f; unsigned int i; } v; v.f = f;
  unsigned int r = v.i + 0x7fffu + ((v.i >> 16) & 1u);
  return (unsigned short)(r >> 16);
}

__device__ __forceinline__ float block_sum256(float v, volatile float* scratch){
  #pragma unroll
  for (int off = 32; off; off >>= 1) v += __shfl_down(v, off, 64);
  int w = threadIdx.x >> 6, lane = threadIdx.x & 63;
  __syncthreads();
  if (lane == 0) scratch[w] = v;
  __syncthreads();
  return scratch[0] + scratch[1] + scratch[2] + scratch[3];
}

// ---------------- encode: phase embedding -> f32 master + bf16 hi/lo ----------------
__global__ void encode_kernel(const int* __restrict__ ids, float* __restrict__ s_f32,
                              unsigned short* __restrict__ hi, unsigned short* __restrict__ lo){
  int row = blockIdx.x;            // 0..4095 = b*S+s
  int t = threadIdx.x;
  float theta = 6.28318530717958647692f * (float)ids[row] / 32000.0f;
  #pragma unroll
  for (int i = 0; i < 2; ++i){
    int kk = t + i * 256;          // 0..511
    float ang = theta * (float)(kk + 1);
    float sv, cv; sincosf(ang, &sv, &cv);
    float c = cv * 0.03125f, s = sv * 0.03125f;   // 1/sqrt(D)
    long b0 = (long)row * DD + kk, b1 = b0 + 512;
    s_f32[b0] = c; s_f32[b1] = s;
    unsigned short ch = f2bf(c); hi[b0] = ch; lo[b0] = f2bf(c - bf2f(ch));
    unsigned short sh = f2bf(s); hi[b1] = sh; lo[b1] = f2bf(s - bf2f(sh));
  }
}

// ---------------- bf16 tiled transpose: in [batch][R][C] -> out [batch][C][R] --------
__global__ void transpose_bf16_kernel(const unsigned short* __restrict__ in,
                                      unsigned short* __restrict__ out, int R, int C){
  __shared__ __align__(16) unsigned short tile[64][80];
  long ib = (long)blockIdx.z * R * C;
  int c0 = blockIdx.x * 64, r0 = blockIdx.y * 64;
  int t = threadIdx.x;
  #pragma unroll
  for (int i = 0; i < 2; ++i){
    int j = t + i * 256; int row = j >> 3, cc = j & 7;
    *(uint4*)&tile[row][cc * 8] = *(const uint4*)(in + ib + (long)(r0 + row) * C + c0 + cc * 8);
  }
  __syncthreads();
  #pragma unroll
  for (int i = 0; i < 2; ++i){
    int j = t + i * 256; int orow = j >> 3, cc = j & 7;
    union { unsigned short u[8]; uint4 v; } tmp;
    #pragma unroll
    for (int e = 0; e < 8; ++e) tmp.u[e] = tile[cc * 8 + e][orow];
    *(uint4*)(out + ib + (long)(c0 + orow) * R + r0 + cc * 8) = tmp.v;
  }
}

// -------- f32 -> bf16 (optionally hi/lo split) transposing convert --------------------
template<bool SPLIT>
__global__ void transpose_f32_bf16_kernel(const float* __restrict__ in,
                                          unsigned short* __restrict__ ohi,
                                          unsigned short* __restrict__ olo, int R, int C){
  __shared__ float tile[64][68];
  long ib = (long)blockIdx.z * R * C;
  int c0 = blockIdx.x * 64, r0 = blockIdx.y * 64;
  int t = threadIdx.x;
  #pragma unroll
  for (int i = 0; i < 4; ++i){
    int j = t + i * 256; int row = j >> 4, cc = j & 15;
    *(float4*)&tile[row][cc * 4] = *(const float4*)(in + ib + (long)(r0 + row) * C + c0 + cc * 4);
  }
  __syncthreads();
  #pragma unroll
  for (int i = 0; i < 2; ++i){
    int j = t + i * 256; int orow = j >> 3, cc = j & 7;
    union { unsigned short u[8]; uint4 v; } th, tl;
    #pragma unroll
    for (int e = 0; e < 8; ++e){
      float v = tile[cc * 8 + e][orow];
      unsigned short h = f2bf(v); th.u[e] = h;
      if (SPLIT) tl.u[e] = f2bf(v - bf2f(h));
    }
    long ob = ib + (long)(c0 + orow) * R + r0 + cc * 8;
    *(uint4*)(ohi + ob) = th.v;
    if (SPLIT) *(uint4*)(olo + ob) = tl.v;
  }
}

// ---------------- the NT GEMM: C[m][n] = alpha * sum_k A[m][k] * Bt[n][k] -------------
// SPLIT: operands given as (hi,lo) pairs -> 3 MFMA products (fp32-class accuracy)
// OUTMODE: 0 = f32 C (+ optional bias), 2 = bf16 hi/lo pair (score path)
// CAUSAL: 0 none; 1 score-mode (skip upper tiles, mask diag tile); 2 pv-mode (k-limit)
template<int SPLIT, int OUTMODE, int CAUSAL>
__global__ __launch_bounds__(256)
void gemm_nt_kernel(const unsigned short* __restrict__ Ahi, const unsigned short* __restrict__ Alo,
                    const unsigned short* __restrict__ Bhi, const unsigned short* __restrict__ Blo,
                    float* __restrict__ C, unsigned short* __restrict__ Chi,
                    unsigned short* __restrict__ Clo, const float* __restrict__ bias,
                    int K, int lda, int ldb, int ldc,
                    long batchA, long batchB, long batchC, float alpha)
{
  const int mt = blockIdx.y, nt = blockIdx.x, bz = blockIdx.z;
  if (CAUSAL == 1 && nt > mt) return;
  const int m0 = mt * 128, n0 = nt * 128;
  int Keff = K;
  if (CAUSAL == 2){ int kl = (mt + 1) * 128; Keff = kl < K ? kl : K; }

  __shared__ __align__(16) unsigned short sA[SPLIT + 1][4][128][8];
  __shared__ __align__(16) unsigned short sB[SPLIT + 1][4][128][8];

  const int tid = threadIdx.x;
  const int lane = tid & 63;
  const int w = tid >> 6;
  const int wr = w >> 1, wc = w & 1;
  const int fr = lane & 15, fc = lane >> 4;

  f32x4 acc[4][4];
  #pragma unroll
  for (int i = 0; i < 4; ++i)
    #pragma unroll
    for (int j = 0; j < 4; ++j) acc[i][j] = (f32x4){0.f, 0.f, 0.f, 0.f};

  const int r0 = tid >> 2, c0 = tid & 3;
  const long aoff = (long)bz * batchA, boff = (long)bz * batchB;
  const unsigned short* pAh = Ahi + aoff + (long)(m0 + r0) * lda + c0 * 8;
  const unsigned short* pBh = Bhi + boff + (long)(n0 + r0) * ldb + c0 * 8;
  const unsigned short* pAl = SPLIT ? (Alo + aoff + (long)(m0 + r0) * lda + c0 * 8) : pAh;
  const unsigned short* pBl = SPLIT ? (Blo + boff + (long)(n0 + r0) * ldb + c0 * 8) : pBh;
  const long ra = 64L * lda, rb = 64L * ldb;

  for (int kt = 0; kt < Keff; kt += 32){
    uint4 a0 = *(const uint4*)(pAh + kt);
    uint4 a1 = *(const uint4*)(pAh + kt + ra);
    uint4 b0 = *(const uint4*)(pBh + kt);
    uint4 b1 = *(const uint4*)(pBh + kt + rb);
    uint4 a2 = a0, a3 = a1, b2 = b0, b3 = b1;
    if (SPLIT){
      a2 = *(const uint4*)(pAl + kt); a3 = *(const uint4*)(pAl + kt + ra);
      b2 = *(const uint4*)(pBl + kt); b3 = *(const uint4*)(pBl + kt + rb);
    }
    __syncthreads();
    *(uint4*)&sA[0][c0][r0][0]      = a0;
    *(uint4*)&sA[0][c0][r0 + 64][0] = a1;
    *(uint4*)&sB[0][c0][r0][0]      = b0;
    *(uint4*)&sB[0][c0][r0 + 64][0] = b1;
    if (SPLIT){
      *(uint4*)&sA[SPLIT][c0][r0][0]      = a2;
      *(uint4*)&sA[SPLIT][c0][r0 + 64][0] = a3;
      *(uint4*)&sB[SPLIT][c0][r0][0]      = b2;
      *(uint4*)&sB[SPLIT][c0][r0 + 64][0] = b3;
    }
    __syncthreads();

    bf16x8 ah[4], al[4];
    #pragma unroll
    for (int mi = 0; mi < 4; ++mi){
      ah[mi] = *(const bf16x8*)&sA[0][fc][wr * 64 + mi * 16 + fr][0];
      if (SPLIT) al[mi] = *(const bf16x8*)&sA[SPLIT][fc][wr * 64 + mi * 16 + fr][0];
    }
    #pragma unroll
    for (int ni = 0; ni < 4; ++ni){
      bf16x8 bh = *(const bf16x8*)&sB[0][fc][wc * 64 + ni * 16 + fr][0];
      if (SPLIT){
        bf16x8 bl = *(const bf16x8*)&sB[SPLIT][fc][wc * 64 + ni * 16 + fr][0];
        #pragma unroll
        for (int mi = 0; mi < 4; ++mi){
          acc[mi][ni] = __builtin_amdgcn_mfma_f32_16x16x32_bf16(ah[mi], bh, acc[mi][ni], 0, 0, 0);
          acc[mi][ni] = __builtin_amdgcn_mfma_f32_16x16x32_bf16(ah[mi], bl, acc[mi][ni], 0, 0, 0);
          acc[mi][ni] = __builtin_amdgcn_mfma_f32_16x16x32_bf16(al[mi], bh, acc[mi][ni], 0, 0, 0);
        }
      } else {
        #pragma unroll
        for (int mi = 0; mi < 4; ++mi)
          acc[mi][ni] = __builtin_amdgcn_mfma_f32_16x16x32_bf16(ah[mi], bh, acc[mi][ni], 0, 0, 0);
      }
    }
  }

  const long coff = (long)bz * batchC;
  const int rb0 = m0 + wr * 64 + fc * 4;   // + mi*16 + r   (C: row=(lane>>4)*4+reg)
  const int cb0 = n0 + wc * 64 + fr;       // + ni*16       (C: col=lane&15)
  #pragma unroll
  for (int mi = 0; mi < 4; ++mi){
    #pragma unroll
    for (int ni = 0; ni < 4; ++ni){
      #pragma unroll
      for (int r = 0; r < 4; ++r){
        int row = rb0 + mi * 16 + r;
        int col = cb0 + ni * 16;
        float v = acc[mi][ni][r] * alpha;
        long idx = coff + (long)row * ldc + col;
        if (OUTMODE == 0){
          if (bias) v += bias[col];
          C[idx] = v;
        } else {
          if (CAUSAL == 1 && col > row) v = 0.0f;   // causal mask (k > q)
          unsigned short h = f2bf(v);
          Chi[idx] = h;
          Clo[idx] = f2bf(v - bf2f(h));
        }
      }
    }
  }
}

// ---------------- elementwise / reduction kernels ------------------------------------
__global__ void mid_kernel(const float* __restrict__ s, const float* __restrict__ k1,
                           unsigned short* __restrict__ hi, unsigned short* __restrict__ lo){
  long i = ((long)blockIdx.x * 256 + threadIdx.x) * 4;
  float4 sv = *(const float4*)(s + i), kv = *(const float4*)(k1 + i);
  float v0 = sv.x + DT_STEP * kv.x, v1 = sv.y + DT_STEP * kv.y;
  float v2 = sv.z + DT_STEP * kv.z, v3 = sv.w + DT_STEP * kv.w;
  ushort4 hv, lv;
  hv.x = f2bf(v0); lv.x = f2bf(v0 - bf2f(hv.x));
  hv.y = f2bf(v1); lv.y = f2bf(v1 - bf2f(hv.y));
  hv.z = f2bf(v2); lv.z = f2bf(v2 - bf2f(hv.z));
  hv.w = f2bf(v3); lv.w = f2bf(v3 - bf2f(hv.w));
  *(ushort4*)(hi + i) = hv; *(ushort4*)(lo + i) = lv;
}

__global__ void ev_energy_kernel(const float* __restrict__ s, const float* __restrict__ k1,
                                 float* __restrict__ k2, float* __restrict__ energy){
  int row = blockIdx.x, t = threadIdx.x;
  long base = (long)row * DD + t * 4;
  float4 sv = *(const float4*)(s + base);
  float4 av = *(const float4*)(k1 + base);
  float4 bv = *(const float4*)(k2 + base);
  float4 ev;
  ev.x = sv.x + HALF_DT * (av.x + bv.x);
  ev.y = sv.y + HALF_DT * (av.y + bv.y);
  ev.z = sv.z + HALF_DT * (av.z + bv.z);
  ev.w = sv.w + HALF_DT * (av.w + bv.w);
  *(float4*)(k2 + base) = ev;   // ev stored in-place over k2
  __shared__ float scratch[4];
  float n2 = block_sum256(ev.x*ev.x + ev.y*ev.y + ev.z*ev.z + ev.w*ev.w, scratch);
  if (t == 0) energy[row] = sqrtf(n2);
}

__global__ void mean_energy_kernel(const float* __restrict__ energy, float* __restrict__ thr){
  int b = blockIdx.x, t = threadIdx.x;
  float s = 0.f;
  for (int j = t; j < SS; j += 256) s += energy[b * SS + j];
  __shared__ float scratch[4];
  float tot = block_sum256(s, scratch);
  if (t == 0) thr[b] = tot * (1.0f / SS);
}

__global__ void tunnel_kernel(const float* __restrict__ ev, const float* __restrict__ energy,
                              const float* __restrict__ thr,
                              unsigned short* __restrict__ hi, unsigned short* __restrict__ lo){
  int row = blockIdx.x, t = threadIdx.x;
  float scale = (energy[row] < thr[row >> 11]) ? TUNNEL_SCALE : 1.0f;
  long base = (long)row * DD + t * 4;
  float4 v = *(const float4*)(ev + base);
  v.x *= scale; v.y *= scale; v.z *= scale; v.w *= scale;
  ushort4 hv, lv;
  hv.x = f2bf(v.x); lv.x = f2bf(v.x - bf2f(hv.x));
  hv.y = f2bf(v.y); lv.y = f2bf(v.y - bf2f(hv.y));
  hv.z = f2bf(v.z); lv.z = f2bf(v.z - bf2f(hv.z));
  hv.w = f2bf(v.w); lv.w = f2bf(v.w - bf2f(hv.w));
  *(ushort4*)(hi + base) = hv; *(ushort4*)(lo + base) = lv;
}

__global__ void ln_kernel(const float* __restrict__ h, const float* __restrict__ w,
                          const float* __restrict__ b, float* __restrict__ s_f32,
                          unsigned short* __restrict__ hi, unsigned short* __restrict__ lo){
  int row = blockIdx.x, t = threadIdx.x;
  long base = (long)row * DD + t * 4;
  float4 xv = *(const float4*)(h + base);
  __shared__ float scratch[4];
  float sum = block_sum256(xv.x + xv.y + xv.z + xv.w, scratch);
  float ssq = block_sum256(xv.x*xv.x + xv.y*xv.y + xv.z*xv.z + xv.w*xv.w, scratch);
  float mu = sum * (1.0f / DD);
  float var = ssq * (1.0f / DD) - mu * mu;
  float rstd = rsqrtf(var + 1e-5f);
  float4 wv = *(const float4*)(w + t * 4), bv = *(const float4*)(b + t * 4);
  float y0 = (xv.x - mu) * rstd * wv.x + bv.x;
  float y1 = (xv.y - mu) * rstd * wv.y + bv.y;
  float y2 = (xv.z - mu) * rstd * wv.z + bv.z;
  float y3 = (xv.w - mu) * rstd * wv.w + bv.w;
  float4 o; o.x = y0; o.y = y1; o.z = y2; o.w = y3;
  *(float4*)(s_f32 + base) = o;
  ushort4 hv, lv;
  hv.x = f2bf(y0); lv.x = f2bf(y0 - bf2f(hv.x));
  hv.y = f2bf(y1); lv.y = f2bf(y1 - bf2f(hv.y));
  hv.z = f2bf(y2); lv.z = f2bf(y2 - bf2f(hv.z));
  hv.w = f2bf(y3); lv.w = f2bf(y3 - bf2f(hv.w));
  *(ushort4*)(hi + base) = hv; *(ushort4*)(lo + base) = lv;
}

// final LN + unit-normalize -> bf16 (plain; un-amplified error)
__global__ void fln_kernel(const float* __restrict__ s, const float* __restrict__ w,
                           const float* __restrict__ b, unsigned short* __restrict__ uhi){
  int row = blockIdx.x, t = threadIdx.x;
  long base = (long)row * DD + t * 4;
  float4 xv = *(const float4*)(s + base);
  __shared__ float scratch[4];
  float sum = block_sum256(xv.x + xv.y + xv.z + xv.w, scratch);
  float ssq = block_sum256(xv.x*xv.x + xv.y*xv.y + xv.z*xv.z + xv.w*xv.w, scratch);
  float mu = sum * (1.0f / DD);
  float var = ssq * (1.0f / DD) - mu * mu;
  float rstd = rsqrtf(var + 1e-5f);
  float4 wv = *(const float4*)(w + t * 4), bv = *(const float4*)(b + t * 4);
  float y0 = (xv.x - mu) * rstd * wv.x + bv.x;
  float y1 = (xv.y - mu) * rstd * wv.y + bv.y;
  float y2 = (xv.z - mu) * rstd * wv.z + bv.z;
  float y3 = (xv.w - mu) * rstd * wv.w + bv.w;
  float n2 = block_sum256(y0*y0 + y1*y1 + y2*y2 + y3*y3, scratch);
  float inv = 1.0f / (sqrtf(n2) + 1e-12f);
  ushort4 o;
  o.x = f2bf(y0 * inv); o.y = f2bf(y1 * inv);
  o.z = f2bf(y2 * inv); o.w = f2bf(y3 * inv);
  *(ushort4*)(uhi + base) = o;
}

// ---------------- loss --------------------------------------------------------------
__global__ void loss_rows_kernel(const float* __restrict__ logits, const int* __restrict__ labels,
                                 float* __restrict__ lrow){
  int idx = blockIdx.x;               // 0..4093
  int b = idx / (SS - 1), q = idx - b * (SS - 1);
  const float* rowp = logits + (long)(b * SS + q) * VV;
  int t = threadIdx.x;
  float m = -1e30f, l = 0.f;
  for (int j = t; j < VV / 4; j += 256){
    float4 v = *(const float4*)(rowp + j * 4);
    float mv = fmaxf(fmaxf(v.x, v.y), fmaxf(v.z, v.w));
    if (mv > m){ l *= __expf(m - mv); m = mv; }
    l += __expf(v.x - m) + __expf(v.y - m) + __expf(v.z - m) + __expf(v.w - m);
  }
  __shared__ float sm[256], sl[256];
  sm[t] = m; sl[t] = l;
  __syncthreads();
  for (int off = 128; off; off >>= 1){
    if (t < off){
      float m2 = sm[t + off], l2 = sl[t + off];
      float M = fmaxf(sm[t], m2);
      sl[t] = sl[t] * __expf(sm[t] - M) + l2 * __expf(m2 - M);
      sm[t] = M;
    }
    __syncthreads();
  }
  if (t == 0){
    float lse = sm[0] + __logf(sl[0]);
    float tl = rowp[labels[b * SS + q + 1]];
    lrow[idx] = lse - tl;
  }
}

__global__ void loss_reduce_kernel(const float* __restrict__ lrow, float* __restrict__ dst){
  __shared__ float scratch[4];
  float s = 0.f;
  for (int j = threadIdx.x; j < BB * (SS - 1); j += 256) s += lrow[j];
  float tot = block_sum256(s, scratch);
  if (threadIdx.x == 0) dst[0] = tot / (float)(BB * (SS - 1));
}

// ---------------- launch ------------------------------------------------------------
extern "C" void kernel_launch(void* const* d_in, const int* in_sizes, int n_in,
                              void* d_out, int out_size, void* d_ws, size_t ws_size,
                              hipStream_t stream) {
  const int*   ids    = (const int*)d_in[0];
  const int*   labels = (const int*)d_in[1];
  const float* proj_w = (const float*)d_in[2];
  const float* proj_b = (const float*)d_in[3];
  const float* ln_w   = (const float*)d_in[4];
  const float* ln_b   = (const float*)d_in[5];
  const float* fln_w  = (const float*)d_in[6];
  const float* fln_b  = (const float*)d_in[7];
  const float* out_w  = (const float*)d_in[8];
  float* out = (float*)d_out;

  char* ws = (char*)d_ws;
  float*          s_f32 = (float*)(ws + 0);                    // 16.78 MB
  unsigned short* op_hi = (unsigned short*)(ws + 16777216);    //  8.39 MB (states/mid/ev/u hi)
  unsigned short* op_lo = (unsigned short*)(ws + 25165824);    //  8.39 MB
  unsigned short* T_hi  = (unsigned short*)(ws + 33554432);    //  8.39 MB (transposed operand)
  unsigned short* T_lo  = (unsigned short*)(ws + 41943040);    //  8.39 MB
  float*          k1    = (float*)(ws + 50331648);             // 16.78 MB (also h pre-LN)
  float*          k2    = (float*)(ws + 67108864);             // 16.78 MB (also ev)
  unsigned short* sc_hi = (unsigned short*)(ws + 83886080);    //  8.39 MB (score hi)
  unsigned short* sc_lo = (unsigned short*)(ws + 92274688);    //  8.39 MB
  unsigned short* WhiT  = (unsigned short*)(ws + 100663296);   // 16.78 MB [L][n][k]
  unsigned short* WloT  = (unsigned short*)(ws + 117440512);   // 16.78 MB
  float*          energy= (float*)(ws + 134217728);
  float*          thr   = (float*)(ws + 134234112);
  float*          lrow  = (float*)(ws + 134234368);
  unsigned short* owT   = T_hi;  // 65.54 MB, overlays T/k/score zone (dead at vocab time)

  // proj_w [L][k][n] -> WhiT/WloT [L][n][k] (fp32-split bf16)
  transpose_f32_bf16_kernel<true><<<dim3(16, 16, 8), 256, 0, stream>>>(proj_w, WhiT, WloT, DD, DD);
  // encode
  encode_kernel<<<NROWS, 256, 0, stream>>>(ids, s_f32, op_hi, op_lo);
  transpose_bf16_kernel<<<dim3(16, 32, 2), 256, 0, stream>>>(op_hi, T_hi, SS, DD);
  transpose_bf16_kernel<<<dim3(16, 32, 2), 256, 0, stream>>>(op_lo, T_lo, SS, DD);

  for (int l = 0; l < LL; ++l){
    // score1 = tril(states @ statesT)/32  -> bf16 hi/lo
    gemm_nt_kernel<1, 2, 1><<<dim3(16, 16, 2), 256, 0, stream>>>(
        op_hi, op_lo, op_hi, op_lo, nullptr, sc_hi, sc_lo, nullptr,
        DD, DD, DD, SS, (long)SS * DD, (long)SS * DD, (long)SS * SS, 0.03125f);
    // k1 = score1 @ states
    gemm_nt_kernel<1, 0, 2><<<dim3(8, 16, 2), 256, 0, stream>>>(
        sc_hi, sc_lo, T_hi, T_lo, k1, nullptr, nullptr, nullptr,
        SS, SS, SS, DD, (long)SS * SS, (long)DD * SS, (long)SS * DD, 1.0f);
    // mid = states + dt*k1
    mid_kernel<<<NROWS, 256, 0, stream>>>(s_f32, k1, op_hi, op_lo);
    transpose_bf16_kernel<<<dim3(16, 32, 2), 256, 0, stream>>>(op_hi, T_hi, SS, DD);
    transpose_bf16_kernel<<<dim3(16, 32, 2), 256, 0, stream>>>(op_lo, T_lo, SS, DD);
    // score2 = tril(mid @ midT)/32
    gemm_nt_kernel<1, 2, 1><<<dim3(16, 16, 2), 256, 0, stream>>>(
        op_hi, op_lo, op_hi, op_lo, nullptr, sc_hi, sc_lo, nullptr,
        DD, DD, DD, SS, (long)SS * DD, (long)SS * DD, (long)SS * SS, 0.03125f);
    // k2 = score2 @ mid
    gemm_nt_kernel<1, 0, 2><<<dim3(8, 16, 2), 256, 0, stream>>>(
        sc_hi, sc_lo, T_hi, T_lo, k2, nullptr, nullptr, nullptr,
        SS, SS, SS, DD, (long)SS * SS, (long)DD * SS, (long)SS * DD, 1.0f);
    // ev = states + 0.5*dt*(k1+k2) (in-place over k2) + row energies
    ev_energy_kernel<<<NROWS, 256, 0, stream>>>(s_f32, k1, k2, energy);
    mean_energy_kernel<<<BB, 256, 0, stream>>>(energy, thr);
    tunnel_kernel<<<NROWS, 256, 0, stream>>>(k2, energy, thr, op_hi, op_lo);
    // h = ev @ proj_w[l] + proj_b[l]  (into k1)
    gemm_nt_kernel<1, 0, 0><<<dim3(8, 32, 1), 256, 0, stream>>>(
        op_hi, op_lo, WhiT + (long)l * DD * DD, WloT + (long)l * DD * DD,
        k1, nullptr, nullptr, proj_b + l * DD, DD, DD, DD, DD, 0, 0, 0, 1.0f);
    // states = LN(h)
    ln_kernel<<<NROWS, 256, 0, stream>>>(k1, ln_w + l * DD, ln_b + l * DD, s_f32, op_hi, op_lo);
    if (l < LL - 1){
      transpose_bf16_kernel<<<dim3(16, 32, 2), 256, 0, stream>>>(op_hi, T_hi, SS, DD);
      transpose_bf16_kernel<<<dim3(16, 32, 2), 256, 0, stream>>>(op_lo, T_lo, SS, DD);
    }
  }

  // out_w [k][v] -> owT [v][k] bf16 (plain); u = unit(LN(states)) -> op_hi
  transpose_f32_bf16_kernel<false><<<dim3(500, 16, 1), 256, 0, stream>>>(out_w, owT, nullptr, DD, VV);
  fln_kernel<<<NROWS, 256, 0, stream>>>(s_f32, fln_w, fln_b, op_hi);
  // logits = u @ out_w  (plain bf16)
  gemm_nt_kernel<0, 0, 0><<<dim3(250, 32, 1), 256, 0, stream>>>(
      op_hi, op_hi, owT, owT, out, nullptr, nullptr, nullptr,
      DD, DD, DD, VV, 0, 0, 0, 1.0f);
  // loss
  loss_rows_kernel<<<BB * (SS - 1), 256, 0, stream>>>(out, labels, lrow);
  loss_reduce_kernel<<<1, 256, 0, stream>>>(lrow, out + (long)NROWS * VV);
}

// Round 2
// 3558.547 us; speedup vs baseline: 1.1196x; 1.1196x over previous
//
#include <hip/hip_runtime.h>

#define LL 8
#define DD 1024
#define VV 32000
#define SS 2048
#define BB 2
#define NROWS 4096          // B*S
#define DT_STEP 0.055f      // 0.5*(dt_min+dt_max)
#define HALF_DT 0.0275f
#define TUNNEL_SCALE 1.55f  // 1 + dt/dt_max

typedef __attribute__((ext_vector_type(8))) short bf16x8;
typedef __attribute__((ext_vector_type(4))) float f32x4;

static __device__ __forceinline__ float bf2f(unsigned short u){
  union { unsigned int i; float f; } v; v.i = ((unsigned int)u) << 16; return v.f;
}
static __device__ __forceinline__ unsigned short f2bf(float f){
  union { float f; unsigned int i; } v; v.f = f;
  unsigned int r = v.i + 0x7fffu + ((v.i >> 16) & 1u);
  return (unsigned short)(r >> 16);
}

// async global->LDS, 16B per lane. lds dest must be wave-uniform base; HW adds lane*16.
static __device__ __forceinline__ void gl16(const unsigned short* g, unsigned short* l){
  __builtin_amdgcn_global_load_lds(
      (const __attribute__((address_space(1))) unsigned int*)g,
      (__attribute__((address_space(3))) unsigned int*)l, 16, 0, 0);
}

__device__ __forceinline__ float block_sum256(float v, volatile float* scratch){
  #pragma unroll
  for (int off = 32; off; off >>= 1) v += __shfl_down(v, off, 64);
  int w = threadIdx.x >> 6, lane = threadIdx.x & 63;
  __syncthreads();
  if (lane == 0) scratch[w] = v;
  __syncthreads();
  return scratch[0] + scratch[1] + scratch[2] + scratch[3];
}

// ---------------- encode: phase embedding -> f32 master + bf16 hi/lo ----------------
__global__ void encode_kernel(const int* __restrict__ ids, float* __restrict__ s_f32,
                              unsigned short* __restrict__ hi, unsigned short* __restrict__ lo){
  int row = blockIdx.x;            // 0..4095 = b*S+s
  int t = threadIdx.x;
  float theta = 6.28318530717958647692f * (float)ids[row] / 32000.0f;
  #pragma unroll
  for (int i = 0; i < 2; ++i){
    int kk = t + i * 256;          // 0..511
    float ang = theta * (float)(kk + 1);
    float sv, cv; sincosf(ang, &sv, &cv);
    float c = cv * 0.03125f, s = sv * 0.03125f;   // 1/sqrt(D)
    long b0 = (long)row * DD + kk, b1 = b0 + 512;
    s_f32[b0] = c; s_f32[b1] = s;
    unsigned short ch = f2bf(c); hi[b0] = ch; lo[b0] = f2bf(c - bf2f(ch));
    unsigned short sh = f2bf(s); hi[b1] = sh; lo[b1] = f2bf(s - bf2f(sh));
  }
}

// ---------------- bf16 tiled transpose (hi+lo pair): [b][R][C] -> [b][C][R] ----------
__global__ void transpose_bf16_pair_kernel(const unsigned short* __restrict__ in_hi,
                                           const unsigned short* __restrict__ in_lo,
                                           unsigned short* __restrict__ out_hi,
                                           unsigned short* __restrict__ out_lo,
                                           int R, int C){
  __shared__ __align__(16) unsigned short tile[64][80];
  int zz = blockIdx.z;                       // (batch<<1) | sel
  const unsigned short* in = (zz & 1) ? in_lo : in_hi;
  unsigned short* out = (zz & 1) ? out_lo : out_hi;
  long ib = (long)(zz >> 1) * R * C;
  int c0 = blockIdx.x * 64, r0 = blockIdx.y * 64;
  int t = threadIdx.x;
  #pragma unroll
  for (int i = 0; i < 2; ++i){
    int j = t + i * 256; int row = j >> 3, cc = j & 7;
    *(uint4*)&tile[row][cc * 8] = *(const uint4*)(in + ib + (long)(r0 + row) * C + c0 + cc * 8);
  }
  __syncthreads();
  #pragma unroll
  for (int i = 0; i < 2; ++i){
    int j = t + i * 256; int orow = j >> 3, cc = j & 7;
    union { unsigned short u[8]; uint4 v; } tmp;
    #pragma unroll
    for (int e = 0; e < 8; ++e) tmp.u[e] = tile[cc * 8 + e][orow];
    *(uint4*)(out + ib + (long)(c0 + orow) * R + r0 + cc * 8) = tmp.v;
  }
}

// -------- f32 -> bf16 (optionally hi/lo split) transposing convert --------------------
template<bool SPLIT>
__global__ void transpose_f32_bf16_kernel(const float* __restrict__ in,
                                          unsigned short* __restrict__ ohi,
                                          unsigned short* __restrict__ olo, int R, int C){
  __shared__ float tile[64][68];
  long ib = (long)blockIdx.z * R * C;
  int c0 = blockIdx.x * 64, r0 = blockIdx.y * 64;
  int t = threadIdx.x;
  #pragma unroll
  for (int i = 0; i < 4; ++i){
    int j = t + i * 256; int row = j >> 4, cc = j & 15;
    *(float4*)&tile[row][cc * 4] = *(const float4*)(in + ib + (long)(r0 + row) * C + c0 + cc * 4);
  }
  __syncthreads();
  #pragma unroll
  for (int i = 0; i < 2; ++i){
    int j = t + i * 256; int orow = j >> 3, cc = j & 7;
    union { unsigned short u[8]; uint4 v; } th, tl;
    #pragma unroll
    for (int e = 0; e < 8; ++e){
      float v = tile[cc * 8 + e][orow];
      unsigned short h = f2bf(v); th.u[e] = h;
      if (SPLIT) tl.u[e] = f2bf(v - bf2f(h));
    }
    long ob = ib + (long)(c0 + orow) * R + r0 + cc * 8;
    *(uint4*)(ohi + ob) = th.v;
    if (SPLIT) *(uint4*)(olo + ob) = tl.v;
  }
}

// ---------------- the NT GEMM (m97 structure): C = alpha * A @ B^T --------------------
// 128x128 tile, BK=32, 4 waves, global_load_lds(16B) into linear [128][32] LDS.
// SPLIT: (hi,lo) operand pairs -> 3 MFMA products (fp32-class accuracy)
// OUTMODE: 0 = f32 C (+ optional bias), 2 = bf16 hi/lo pair (score path)
// CAUSAL: 0 none; 1 score-mode (skip upper tiles, mask diag tile); 2 pv-mode (k-limit)
template<int SPLIT, int OUTMODE, int CAUSAL>
__global__ __launch_bounds__(256)
void gemm_nt_kernel(const unsigned short* __restrict__ Ahi, const unsigned short* __restrict__ Alo,
                    const unsigned short* __restrict__ Bhi, const unsigned short* __restrict__ Blo,
                    float* __restrict__ C, unsigned short* __restrict__ Chi,
                    unsigned short* __restrict__ Clo, const float* __restrict__ bias,
                    int K, int lda, int ldb, int ldc, int MT, int NT,
                    long batchA, long batchB, long batchC, float alpha)
{
  const int bz = blockIdx.y;
  // bijective XCD swizzle (m204) + m-fastest supertiling (bands of 8 m-tiles)
  const int nwg = MT * NT;
  const int q = nwg >> 3, r = nwg & 7;
  const int xcd = blockIdx.x & 7, off = blockIdx.x >> 3;
  const int wg = (xcd < r ? xcd * (q + 1) : r * (q + 1) + (xcd - r) * q) + off;
  const int band = wg / (NT << 3), rem = wg - band * (NT << 3);
  const int mt = (band << 3) + (rem & 7), nt = rem >> 3;
  if (CAUSAL == 1 && nt > mt) return;
  const int m0 = mt << 7, n0 = nt << 7;
  int Keff = K;
  if (CAUSAL == 2){ int kl = (mt + 1) << 7; Keff = kl < K ? kl : K; }

  __shared__ __align__(16) unsigned short sA[SPLIT + 1][128][32];
  __shared__ __align__(16) unsigned short sB[SPLIT + 1][128][32];

  const int tid = threadIdx.x;
  const int lane = tid & 63;
  const int w = tid >> 6;
  const int wr = w >> 1, wc = w & 1;
  const int fr = lane & 15, fc = lane >> 4;

  f32x4 acc[4][4];
  #pragma unroll
  for (int i = 0; i < 4; ++i)
    #pragma unroll
    for (int j = 0; j < 4; ++j) acc[i][j] = (f32x4){0.f, 0.f, 0.f, 0.f};

  // staging: thread tid owns 16B chunk tid (+256 for second issue) of each [128][32] tile
  const int srow = tid >> 2, scol = (tid & 3) << 3;
  const long aoff = (long)bz * batchA, boff = (long)bz * batchB;
  const unsigned short* gAh = Ahi + aoff + (long)(m0 + srow) * lda + scol;
  const unsigned short* gBh = Bhi + boff + (long)(n0 + srow) * ldb + scol;
  const unsigned short* gAl = SPLIT ? (Alo + aoff + (long)(m0 + srow) * lda + scol) : gAh;
  const unsigned short* gBl = SPLIT ? (Blo + boff + (long)(n0 + srow) * ldb + scol) : gBh;
  const long ra = 64L * lda, rb = 64L * ldb;
  unsigned short* lA = &sA[0][0][0] + ((tid & 192) << 3);  // wave-uniform: (w*64)*8 elems
  unsigned short* lB = &sB[0][0][0] + ((tid & 192) << 3);

  for (int kt = 0; kt < Keff; kt += 32){
    __syncthreads();                       // prev compute done before DMA overwrites LDS
    gl16(gAh + kt,      lA);
    gl16(gAh + kt + ra, lA + 2048);
    gl16(gBh + kt,      lB);
    gl16(gBh + kt + rb, lB + 2048);
    if (SPLIT){
      gl16(gAl + kt,      lA + 4096);
      gl16(gAl + kt + ra, lA + 4096 + 2048);
      gl16(gBl + kt,      lB + 4096);
      gl16(gBl + kt + rb, lB + 4096 + 2048);
    }
    __syncthreads();                       // vmcnt(0) drain: tile ready

    const int ar = wr * 64 + fr;
    bf16x8 ah[4], al[4];
    #pragma unroll
    for (int mi = 0; mi < 4; ++mi){
      ah[mi] = *(const bf16x8*)&sA[0][ar + mi * 16][fc * 8];
      if (SPLIT) al[mi] = *(const bf16x8*)&sA[1][ar + mi * 16][fc * 8];
    }
    #pragma unroll
    for (int ni = 0; ni < 4; ++ni){
      const int br = wc * 64 + ni * 16 + fr;
      bf16x8 bh = *(const bf16x8*)&sB[0][br][fc * 8];
      if (SPLIT){
        bf16x8 bl = *(const bf16x8*)&sB[1][br][fc * 8];
        #pragma unroll
        for (int mi = 0; mi < 4; ++mi){
          acc[mi][ni] = __builtin_amdgcn_mfma_f32_16x16x32_bf16(ah[mi], bh, acc[mi][ni], 0, 0, 0);
          acc[mi][ni] = __builtin_amdgcn_mfma_f32_16x16x32_bf16(ah[mi], bl, acc[mi][ni], 0, 0, 0);
          acc[mi][ni] = __builtin_amdgcn_mfma_f32_16x16x32_bf16(al[mi], bh, acc[mi][ni], 0, 0, 0);
        }
      } else {
        #pragma unroll
        for (int mi = 0; mi < 4; ++mi)
          acc[mi][ni] = __builtin_amdgcn_mfma_f32_16x16x32_bf16(ah[mi], bh, acc[mi][ni], 0, 0, 0);
      }
    }
  }

  const long coff = (long)bz * batchC;
  const int rb0 = m0 + wr * 64 + fc * 4;   // + mi*16 + r   (C: row=(lane>>4)*4+reg)
  const int cb0 = n0 + wc * 64 + fr;       // + ni*16       (C: col=lane&15)
  #pragma unroll
  for (int mi = 0; mi < 4; ++mi){
    #pragma unroll
    for (int ni = 0; ni < 4; ++ni){
      #pragma unroll
      for (int rg = 0; rg < 4; ++rg){
        int row = rb0 + mi * 16 + rg;
        int col = cb0 + ni * 16;
        float v = acc[mi][ni][rg] * alpha;
        long idx = coff + (long)row * ldc + col;
        if (OUTMODE == 0){
          if (bias) v += bias[col];
          C[idx] = v;
        } else {
          if (CAUSAL == 1 && col > row) v = 0.0f;   // causal mask (k > q)
          unsigned short h = f2bf(v);
          Chi[idx] = h;
          Clo[idx] = f2bf(v - bf2f(h));
        }
      }
    }
  }
}

// ---------------- elementwise / reduction kernels ------------------------------------
__global__ void mid_kernel(const float* __restrict__ s, const float* __restrict__ k1,
                           unsigned short* __restrict__ hi, unsigned short* __restrict__ lo){
  long i = ((long)blockIdx.x * 256 + threadIdx.x) * 4;
  float4 sv = *(const float4*)(s + i), kv = *(const float4*)(k1 + i);
  float v0 = sv.x + DT_STEP * kv.x, v1 = sv.y + DT_STEP * kv.y;
  float v2 = sv.z + DT_STEP * kv.z, v3 = sv.w + DT_STEP * kv.w;
  ushort4 hv, lv;
  hv.x = f2bf(v0); lv.x = f2bf(v0 - bf2f(hv.x));
  hv.y = f2bf(v1); lv.y = f2bf(v1 - bf2f(hv.y));
  hv.z = f2bf(v2); lv.z = f2bf(v2 - bf2f(hv.z));
  hv.w = f2bf(v3); lv.w = f2bf(v3 - bf2f(hv.w));
  *(ushort4*)(hi + i) = hv; *(ushort4*)(lo + i) = lv;
}

__global__ void ev_energy_kernel(const float* __restrict__ s, const float* __restrict__ k1,
                                 float* __restrict__ k2, float* __restrict__ energy){
  int row = blockIdx.x, t = threadIdx.x;
  long base = (long)row * DD + t * 4;
  float4 sv = *(const float4*)(s + base);
  float4 av = *(const float4*)(k1 + base);
  float4 bv = *(const float4*)(k2 + base);
  float4 ev;
  ev.x = sv.x + HALF_DT * (av.x + bv.x);
  ev.y = sv.y + HALF_DT * (av.y + bv.y);
  ev.z = sv.z + HALF_DT * (av.z + bv.z);
  ev.w = sv.w + HALF_DT * (av.w + bv.w);
  *(float4*)(k2 + base) = ev;   // ev stored in-place over k2
  __shared__ float scratch[4];
  float n2 = block_sum256(ev.x*ev.x + ev.y*ev.y + ev.z*ev.z + ev.w*ev.w, scratch);
  if (t == 0) energy[row] = sqrtf(n2);
}

__global__ void mean_energy_kernel(const float* __restrict__ energy, float* __restrict__ thr){
  int b = blockIdx.x, t = threadIdx.x;
  float s = 0.f;
  for (int j = t; j < SS; j += 256) s += energy[b * SS + j];
  __shared__ float scratch[4];
  float tot = block_sum256(s, scratch);
  if (t == 0) thr[b] = tot * (1.0f / SS);
}

__global__ void tunnel_kernel(const float* __restrict__ ev, const float* __restrict__ energy,
                              const float* __restrict__ thr,
                              unsigned short* __restrict__ hi, unsigned short* __restrict__ lo){
  int row = blockIdx.x, t = threadIdx.x;
  float scale = (energy[row] < thr[row >> 11]) ? TUNNEL_SCALE : 1.0f;
  long base = (long)row * DD + t * 4;
  float4 v = *(const float4*)(ev + base);
  v.x *= scale; v.y *= scale; v.z *= scale; v.w *= scale;
  ushort4 hv, lv;
  hv.x = f2bf(v.x); lv.x = f2bf(v.x - bf2f(hv.x));
  hv.y = f2bf(v.y); lv.y = f2bf(v.y - bf2f(hv.y));
  hv.z = f2bf(v.z); lv.z = f2bf(v.z - bf2f(hv.z));
  hv.w = f2bf(v.w); lv.w = f2bf(v.w - bf2f(hv.w));
  *(ushort4*)(hi + base) = hv; *(ushort4*)(lo + base) = lv;
}

__global__ void ln_kernel(const float* __restrict__ h, const float* __restrict__ w,
                          const float* __restrict__ b, float* __restrict__ s_f32,
                          unsigned short* __restrict__ hi, unsigned short* __restrict__ lo){
  int row = blockIdx.x, t = threadIdx.x;
  long base = (long)row * DD + t * 4;
  float4 xv = *(const float4*)(h + base);
  __shared__ float scratch[4];
  float sum = block_sum256(xv.x + xv.y + xv.z + xv.w, scratch);
  float ssq = block_sum256(xv.x*xv.x + xv.y*xv.y + xv.z*xv.z + xv.w*xv.w, scratch);
  float mu = sum * (1.0f / DD);
  float var = ssq * (1.0f / DD) - mu * mu;
  float rstd = rsqrtf(var + 1e-5f);
  float4 wv = *(const float4*)(w + t * 4), bv = *(const float4*)(b + t * 4);
  float y0 = (xv.x - mu) * rstd * wv.x + bv.x;
  float y1 = (xv.y - mu) * rstd * wv.y + bv.y;
  float y2 = (xv.z - mu) * rstd * wv.z + bv.z;
  float y3 = (xv.w - mu) * rstd * wv.w + bv.w;
  float4 o; o.x = y0; o.y = y1; o.z = y2; o.w = y3;
  *(float4*)(s_f32 + base) = o;
  ushort4 hv, lv;
  hv.x = f2bf(y0); lv.x = f2bf(y0 - bf2f(hv.x));
  hv.y = f2bf(y1); lv.y = f2bf(y1 - bf2f(hv.y));
  hv.z = f2bf(y2); lv.z = f2bf(y2 - bf2f(hv.z));
  hv.w = f2bf(y3); lv.w = f2bf(y3 - bf2f(hv.w));
  *(ushort4*)(hi + base) = hv; *(ushort4*)(lo + base) = lv;
}

// final LN + unit-normalize -> bf16 (plain; un-amplified error)
__global__ void fln_kernel(const float* __restrict__ s, const float* __restrict__ w,
                           const float* __restrict__ b, unsigned short* __restrict__ uhi){
  int row = blockIdx.x, t = threadIdx.x;
  long base = (long)row * DD + t * 4;
  float4 xv = *(const float4*)(s + base);
  __shared__ float scratch[4];
  float sum = block_sum256(xv.x + xv.y + xv.z + xv.w, scratch);
  float ssq = block_sum256(xv.x*xv.x + xv.y*xv.y + xv.z*xv.z + xv.w*xv.w, scratch);
  float mu = sum * (1.0f / DD);
  float var = ssq * (1.0f / DD) - mu * mu;
  float rstd = rsqrtf(var + 1e-5f);
  float4 wv = *(const float4*)(w + t * 4), bv = *(const float4*)(b + t * 4);
  float y0 = (xv.x - mu) * rstd * wv.x + bv.x;
  float y1 = (xv.y - mu) * rstd * wv.y + bv.y;
  float y2 = (xv.z - mu) * rstd * wv.z + bv.z;
  float y3 = (xv.w - mu) * rstd * wv.w + bv.w;
  float n2 = block_sum256(y0*y0 + y1*y1 + y2*y2 + y3*y3, scratch);
  float inv = 1.0f / (sqrtf(n2) + 1e-12f);
  ushort4 o;
  o.x = f2bf(y0 * inv); o.y = f2bf(y1 * inv);
  o.z = f2bf(y2 * inv); o.w = f2bf(y3 * inv);
  *(ushort4*)(uhi + base) = o;
}

// ---------------- loss --------------------------------------------------------------
__global__ void loss_rows_kernel(const float* __restrict__ logits, const int* __restrict__ labels,
                                 float* __restrict__ lrow){
  int idx = blockIdx.x;               // 0..4093
  int b = idx / (SS - 1), q = idx - b * (SS - 1);
  const float* rowp = logits + (long)(b * SS + q) * VV;
  int t = threadIdx.x;
  float m = -1e30f, l = 0.f;
  for (int j = t; j < VV / 4; j += 256){
    float4 v = *(const float4*)(rowp + j * 4);
    float mv = fmaxf(fmaxf(v.x, v.y), fmaxf(v.z, v.w));
    if (mv > m){ l *= __expf(m - mv); m = mv; }
    l += __expf(v.x - m) + __expf(v.y - m) + __expf(v.z - m) + __expf(v.w - m);
  }
  __shared__ float sm[256], sl[256];
  sm[t] = m; sl[t] = l;
  __syncthreads();
  for (int off = 128; off; off >>= 1){
    if (t < off){
      float m2 = sm[t + off], l2 = sl[t + off];
      float M = fmaxf(sm[t], m2);
      sl[t] = sl[t] * __expf(sm[t] - M) + l2 * __expf(m2 - M);
      sm[t] = M;
    }
    __syncthreads();
  }
  if (t == 0){
    float lse = sm[0] + __logf(sl[0]);
    float tl = rowp[labels[b * SS + q + 1]];
    lrow[idx] = lse - tl;
  }
}

__global__ void loss_reduce_kernel(const float* __restrict__ lrow, float* __restrict__ dst){
  __shared__ float scratch[4];
  float s = 0.f;
  for (int j = threadIdx.x; j < BB * (SS - 1); j += 256) s += lrow[j];
  float tot = block_sum256(s, scratch);
  if (threadIdx.x == 0) dst[0] = tot / (float)(BB * (SS - 1));
}

// ---------------- launch ------------------------------------------------------------
extern "C" void kernel_launch(void* const* d_in, const int* in_sizes, int n_in,
                              void* d_out, int out_size, void* d_ws, size_t ws_size,
                              hipStream_t stream) {
  const int*   ids    = (const int*)d_in[0];
  const int*   labels = (const int*)d_in[1];
  const float* proj_w = (const float*)d_in[2];
  const float* proj_b = (const float*)d_in[3];
  const float* ln_w   = (const float*)d_in[4];
  const float* ln_b   = (const float*)d_in[5];
  const float* fln_w  = (const float*)d_in[6];
  const float* fln_b  = (const float*)d_in[7];
  const float* out_w  = (const float*)d_in[8];
  float* out = (float*)d_out;

  char* ws = (char*)d_ws;
  float*          s_f32 = (float*)(ws + 0);                    // 16.78 MB
  unsigned short* op_hi = (unsigned short*)(ws + 16777216);    //  8.39 MB (states/mid/ev/u hi)
  unsigned short* op_lo = (unsigned short*)(ws + 25165824);    //  8.39 MB
  unsigned short* T_hi  = (unsigned short*)(ws + 33554432);    //  8.39 MB (transposed operand)
  unsigned short* T_lo  = (unsigned short*)(ws + 41943040);    //  8.39 MB
  float*          k1    = (float*)(ws + 50331648);             // 16.78 MB (also h pre-LN)
  float*          k2    = (float*)(ws + 67108864);             // 16.78 MB (also ev)
  unsigned short* sc_hi = (unsigned short*)(ws + 83886080);    //  8.39 MB (score hi)
  unsigned short* sc_lo = (unsigned short*)(ws + 92274688);    //  8.39 MB
  unsigned short* WhiT  = (unsigned short*)(ws + 100663296);   // 16.78 MB [L][n][k]
  unsigned short* WloT  = (unsigned short*)(ws + 117440512);   // 16.78 MB
  float*          energy= (float*)(ws + 134217728);
  float*          thr   = (float*)(ws + 134234112);
  float*          lrow  = (float*)(ws + 134234368);
  unsigned short* owT   = T_hi;  // 65.54 MB, overlays T/k/score zone (dead at vocab time)

  // proj_w [L][k][n] -> WhiT/WloT [L][n][k] (fp32-split bf16)
  transpose_f32_bf16_kernel<true><<<dim3(16, 16, 8), 256, 0, stream>>>(proj_w, WhiT, WloT, DD, DD);
  // encode
  encode_kernel<<<NROWS, 256, 0, stream>>>(ids, s_f32, op_hi, op_lo);
  transpose_bf16_pair_kernel<<<dim3(16, 32, 4), 256, 0, stream>>>(op_hi, op_lo, T_hi, T_lo, SS, DD);

  for (int l = 0; l < LL; ++l){
    // score1 = tril(states @ statesT)/32  -> bf16 hi/lo
    gemm_nt_kernel<1, 2, 1><<<dim3(256, 2), 256, 0, stream>>>(
        op_hi, op_lo, op_hi, op_lo, nullptr, sc_hi, sc_lo, nullptr,
        DD, DD, DD, SS, 16, 16, (long)SS * DD, (long)SS * DD, (long)SS * SS, 0.03125f);
    // k1 = score1 @ states
    gemm_nt_kernel<1, 0, 2><<<dim3(128, 2), 256, 0, stream>>>(
        sc_hi, sc_lo, T_hi, T_lo, k1, nullptr, nullptr, nullptr,
        SS, SS, SS, DD, 16, 8, (long)SS * SS, (long)DD * SS, (long)SS * DD, 1.0f);
    // mid = states + dt*k1
    mid_kernel<<<NROWS, 256, 0, stream>>>(s_f32, k1, op_hi, op_lo);
    transpose_bf16_pair_kernel<<<dim3(16, 32, 4), 256, 0, stream>>>(op_hi, op_lo, T_hi, T_lo, SS, DD);
    // score2 = tril(mid @ midT)/32
    gemm_nt_kernel<1, 2, 1><<<dim3(256, 2), 256, 0, stream>>>(
        op_hi, op_lo, op_hi, op_lo, nullptr, sc_hi, sc_lo, nullptr,
        DD, DD, DD, SS, 16, 16, (long)SS * DD, (long)SS * DD, (long)SS * SS, 0.03125f);
    // k2 = score2 @ mid
    gemm_nt_kernel<1, 0, 2><<<dim3(128, 2), 256, 0, stream>>>(
        sc_hi, sc_lo, T_hi, T_lo, k2, nullptr, nullptr, nullptr,
        SS, SS, SS, DD, 16, 8, (long)SS * SS, (long)DD * SS, (long)SS * DD, 1.0f);
    // ev = states + 0.5*dt*(k1+k2) (in-place over k2) + row energies
    ev_energy_kernel<<<NROWS, 256, 0, stream>>>(s_f32, k1, k2, energy);
    mean_energy_kernel<<<BB, 256, 0, stream>>>(energy, thr);
    tunnel_kernel<<<NROWS, 256, 0, stream>>>(k2, energy, thr, op_hi, op_lo);
    // h = ev @ proj_w[l] + proj_b[l]  (into k1)
    gemm_nt_kernel<1, 0, 0><<<dim3(256, 1), 256, 0, stream>>>(
        op_hi, op_lo, WhiT + (long)l * DD * DD, WloT + (long)l * DD * DD,
        k1, nullptr, nullptr, proj_b + l * DD, DD, DD, DD, DD, 32, 8, 0, 0, 0, 1.0f);
    // states = LN(h)
    ln_kernel<<<NROWS, 256, 0, stream>>>(k1, ln_w + l * DD, ln_b + l * DD, s_f32, op_hi, op_lo);
    if (l < LL - 1){
      transpose_bf16_pair_kernel<<<dim3(16, 32, 4), 256, 0, stream>>>(op_hi, op_lo, T_hi, T_lo, SS, DD);
    }
  }

  // out_w [k][v] -> owT [v][k] bf16 (plain); u = unit(LN(states)) -> op_hi
  transpose_f32_bf16_kernel<false><<<dim3(500, 16, 1), 256, 0, stream>>>(out_w, owT, nullptr, DD, VV);
  fln_kernel<<<NROWS, 256, 0, stream>>>(s_f32, fln_w, fln_b, op_hi);
  // logits = u @ out_w  (plain bf16)
  gemm_nt_kernel<0, 0, 0><<<dim3(8000, 1), 256, 0, stream>>>(
      op_hi, op_hi, owT, owT, out, nullptr, nullptr, nullptr,
      DD, DD, DD, VV, 32, 250, 0, 0, 0, 1.0f);
  // loss
  loss_rows_kernel<<<BB * (SS - 1), 256, 0, stream>>>(out, labels, lrow);
  loss_reduce_kernel<<<1, 256, 0, stream>>>(lrow, out + (long)NROWS * VV);
}